// Round 14
// baseline (153.781 us; speedup 1.0000x reference)
//
#include <hip/hip_runtime.h>
#include <hip/hip_bf16.h>
#include <hip/hip_fp8.h>

typedef __attribute__((ext_vector_type(4))) int i32x4;
typedef __attribute__((ext_vector_type(8))) int i32x8;
typedef __attribute__((ext_vector_type(16))) float f32x16;

#define MARGIN 0.3f
#define BIGF 3.0e38f

__device__ __forceinline__ f32x16 mx_mfma(i32x8 a, i32x8 b, f32x16 c) {
    return __builtin_amdgcn_mfma_scale_f32_32x32x64_f8f6f4(
        a, b, c, 0 /*A fmt fp8*/, 0 /*B fmt fp8*/,
        0, 127 /*scale A = 2^0*/, 0, 127 /*scale B = 2^0*/);
}

// 32B fragment load (one cell slice for this lane): two dwordx4.
__device__ __forceinline__ i32x8 ld32(const unsigned char* p) {
    i32x4 lo = *(const i32x4*)p;
    i32x4 hi = *(const i32x4*)(p + 16);
    return __builtin_shufflevector(lo, hi, 0, 1, 2, 3, 4, 5, 6, 7);
}

// Spin until n consecutive panel flags are set. Relaxed agent polls +
// s_sleep (low traffic); caller issues the acquire fence afterwards.
__device__ __forceinline__ void waitpan(const unsigned* f, int n) {
    for (int i = 0; i < n; i++)
        while (__hip_atomic_load(&f[i], __ATOMIC_RELAXED,
                                 __HIP_MEMORY_SCOPE_AGENT) == 0u)
            __builtin_amdgcn_s_sleep(2);
}

// FUSED convert + TRIANGULAR fp8-MX GEMM-reduce (v9).
// R13 post-mortem: depth-2 materialized partially (VGPR 88) and time was
// unchanged (61.7 vs 59.6 noise) -> the Little's-law/ILP model is
// falsified; seven structures (LDS-lockstep, 4-phase vmcnt, reg depth
// 1/2/3/4, triangle, swizzles) all land 59.6-66 us with NO saturated
// counter -> ~60 us is this gemm's empirical floor for reachable
// plain-HIP structures. Remaining controllable time: the convert->gemm
// stream serialization (gemm waits for ALL 4096 rows; each tile needs
// only 8 of 128 panels).
// v9: single kernel. Blocks 0..127 convert one 32-row panel each (4
// waves x 8 rows; per-row body BYTE-IDENTICAL to the R4-verified convert
// incl. nrm/ap/an init), then threadfence + release flags[panel]. Every
// block then spins on its tile's 8 (full) / 4 (quarter) panel flags
// (relaxed polls + s_sleep, one acquire fence), and runs the R12-exact
// gemm engine (best measured: 59.6 us steady; depth-1 unroll-4).
// Deadlock safety WITHOUT dispatch-order assumptions (G16):
// __launch_bounds__(256,3) + grid 576 <= 3*256 -> all blocks
// co-resident -> every producer runs concurrently with every spinner.
// flags+cnt zeroed by a 516-B hipMemsetAsync before launch (graph-node
// legal; also removes the old cnt-zeroing race).
// Carried verbatim (R12-verified, absmax 0): triangle unrank, 512 full
// 128^2 + 64 quarter 64^2 blocks, fragment-native cells, C/D map
// col=lane&31 row=(reg&3)+8*(reg>>2)+4*h, dual-sided epilogue, monotone
// uint atomics, counter-gated fused loss. Numerics bit-identical.
__global__ __launch_bounds__(256, 3) void fused_kernel(
    const float* __restrict__ X, unsigned char* __restrict__ Xf,
    float* __restrict__ nrm, const int* __restrict__ Y,
    unsigned* __restrict__ ap, unsigned* __restrict__ an,
    unsigned* __restrict__ flags, unsigned* __restrict__ cnt,
    float* __restrict__ out, int N, int K) {
    __shared__ int sYr[128], sYc[128];
    __shared__ float sNr[128], sNc[128];
    __shared__ float redmax[4][64], redmin[4][64];  // row-side, per wave
    __shared__ float cmax[4][64], cmin[4][64];      // col-side, per wave
    __shared__ float lsum[4];
    __shared__ unsigned s_done;

    const int tid = threadIdx.x;
    const int wave = tid >> 6;
    const int lane = tid & 63;
    const int m = lane & 31;   // col within 32x32 subtile (outputs)
    const int h = lane >> 5;   // row-group (outputs)
    const int wr = wave >> 1;  // wave row (0..1)
    const int wc = wave & 1;   // wave col (0..1)
    const int bid = blockIdx.x;

    const int NPAN = N >> 5;             // 128 panels of 32 rows
    const int NB = N >> 7;               // 32
    const int ntri = NB * (NB + 1) / 2;  // 528
    const int FULLB = ntri - 16;         // 512 full-tile blocks
    const int nt = K >> 6;               // 32 k64-steps

    // ---------------- CONVERT PHASE (blocks 0..NPAN-1) ----------------
    // Block b converts panel b (rows 32b..32b+31): wave w does rows
    // w, w+4, ..., w+28. Per-row body identical to the standalone
    // convert kernel (same wave-per-row lane math -> bitwise-equal nrm).
    if (bid < NPAN) {
#pragma unroll 1
        for (int r = wave; r < 32; r += 4) {
            const int row = (bid << 5) + r;
            const float* xr = X + (size_t)row * K;
            const size_t pbase = ((size_t)(row >> 5)) << 16;  // p * 65536
            const int rsub = row & 31;
            float s = 0.0f;
            for (int c = lane * 8; c < K; c += 64 * 8) {
                float4 v0 = *(const float4*)(xr + c);
                float4 v1 = *(const float4*)(xr + c + 4);
                float f[8] = {v0.x, v0.y, v0.z, v0.w, v1.x, v1.y, v1.z, v1.w};
                union { unsigned char b[8]; uint2 u; } p;
#pragma unroll
                for (int i = 0; i < 8; i++) {
                    __hip_fp8_e4m3 q(f[i]);       // OCP e4m3, RNE+saturate
                    p.b[i] = q.__x;
                    float d = (float)q;           // decoded value
                    s += d * d;
                }
                const int lslot = rsub + (((c >> 5) & 1) << 5);
                unsigned char* dst = Xf + pbase + ((size_t)(c >> 6) << 11)
                                     + (lslot << 5) + (c & 31);
                *(uint2*)dst = p.u;
            }
            for (int off = 32; off > 0; off >>= 1) s += __shfl_xor(s, off, 64);
            if (lane == 0) {
                nrm[row] = s;
                ap[row] = 0u;           // dist_ap >= 0 (self is a positive)
                an[row] = 0x7F800000u;  // +inf
            }
        }
        __syncthreads();  // all 4 waves' Xf/nrm/ap/an stores issued
        if (tid == 0) {
            __threadfence();  // agent-visible before the flag
            __hip_atomic_store(&flags[bid], 1u, __ATOMIC_RELEASE,
                               __HIP_MEMORY_SCOPE_AGENT);
        }
    }

    // ---------------- GEMM PHASE (all 576 blocks) ---------------------
    if (bid < FULLB) {
        // ---------------- FULL 128^2 TILE PATH ------------------------
        int bi = bid, ti = 0;
        while (bi >= NB - ti) { bi -= NB - ti; ti++; }
        const int tj = ti + bi;
        const int rowBase = ti << 7;
        const int colBase = tj << 7;

        // Wait for the 4 row panels + 4 col panels of this tile.
        if (tid == 0) {
            waitpan(flags + (rowBase >> 5), 4);
            waitpan(flags + (colBase >> 5), 4);
            __threadfence();  // acquire: Xf/nrm/ap/an of those panels
        }
        __syncthreads();

        if (tid < 128) {
            sYr[tid] = Y[rowBase + tid];
            sNr[tid] = nrm[rowBase + tid];
        } else {
            const int t0 = tid - 128;
            sYc[t0] = Y[colBase + t0];
            sNc[t0] = nrm[colBase + t0];
        }

        f32x16 acc[2][2];
#pragma unroll
        for (int si = 0; si < 2; si++)
#pragma unroll
            for (int sj = 0; sj < 2; sj++)
#pragma unroll
                for (int rr = 0; rr < 16; rr++) acc[si][sj][rr] = 0.0f;

        const unsigned char* pa[2];
        const unsigned char* pb[2];
#pragma unroll
        for (int si = 0; si < 2; si++)
            pa[si] = Xf + (((size_t)(rowBase >> 5) + wr * 2 + si) << 16) + lane * 32;
#pragma unroll
        for (int sj = 0; sj < 2; sj++)
            pb[sj] = Xf + (((size_t)(colBase >> 5) + wc * 2 + sj) << 16) + lane * 32;

#pragma unroll 4
        for (int t = 0; t < nt; t++) {
            const size_t off = (size_t)t << 11;
            i32x8 a0 = ld32(pa[0] + off);
            i32x8 a1 = ld32(pa[1] + off);
            i32x8 b0 = ld32(pb[0] + off);
            i32x8 b1 = ld32(pb[1] + off);
            acc[0][0] = mx_mfma(a0, b0, acc[0][0]);
            acc[0][1] = mx_mfma(a0, b1, acc[0][1]);
            acc[1][0] = mx_mfma(a1, b0, acc[1][0]);
            acc[1][1] = mx_mfma(a1, b1, acc[1][1]);
        }

        __syncthreads();  // sY/sN visible

        float cdp[2] = {-1.0f, -1.0f};
        float cdn[2] = {BIGF, BIGF};
#pragma unroll
        for (int si = 0; si < 2; si++)
#pragma unroll
            for (int reg = 0; reg < 16; reg++) {
                const int row64 = si * 32 + (reg & 3) + 8 * (reg >> 2) + 4 * h;
                const int rIdx = wr * 64 + row64;
                const int yr = sYr[rIdx];
                const float nr = sNr[rIdx];
                float dp = -1.0f, dn = BIGF;
#pragma unroll
                for (int sj = 0; sj < 2; sj++) {
                    const int cIdx = wc * 64 + sj * 32 + m;
                    float d2 = nr + sNc[cIdx] - 2.0f * acc[si][sj][reg];
                    float d = sqrtf(fmaxf(d2, 0.0f));
                    bool same = (yr == sYc[cIdx]);
                    float vp = same ? d : -1.0f;
                    float vn = same ? BIGF : d;
                    dp = fmaxf(dp, vp);
                    dn = fminf(dn, vn);
                    cdp[sj] = fmaxf(cdp[sj], vp);
                    cdn[sj] = fminf(cdn[sj], vn);
                }
                for (int off = 1; off < 32; off <<= 1) {
                    dp = fmaxf(dp, __shfl_xor(dp, off, 64));
                    dn = fminf(dn, __shfl_xor(dn, off, 64));
                }
                if (m == 0) {
                    redmax[wave][row64] = dp;
                    redmin[wave][row64] = dn;
                }
            }
#pragma unroll
        for (int sj = 0; sj < 2; sj++) {
            cdp[sj] = fmaxf(cdp[sj], __shfl_xor(cdp[sj], 32, 64));
            cdn[sj] = fminf(cdn[sj], __shfl_xor(cdn[sj], 32, 64));
            if (h == 0) {
                cmax[wave][sj * 32 + m] = cdp[sj];
                cmin[wave][sj * 32 + m] = cdn[sj];
            }
        }
        __syncthreads();

        if (tid < 128) {
            const int wr2 = tid >> 6, r64 = tid & 63;
            float mx = fmaxf(redmax[wr2 * 2][r64], redmax[wr2 * 2 + 1][r64]);
            float mn = fminf(redmin[wr2 * 2][r64], redmin[wr2 * 2 + 1][r64]);
            atomicMax(&ap[rowBase + tid], __float_as_uint(fmaxf(mx, 0.0f)));
            atomicMin(&an[rowBase + tid], __float_as_uint(mn));
        } else {
            const int t0 = tid - 128;
            const int wc2 = t0 >> 6, c64 = t0 & 63;
            float mx = fmaxf(cmax[wc2][c64], cmax[2 + wc2][c64]);
            float mn = fminf(cmin[wc2][c64], cmin[2 + wc2][c64]);
            atomicMax(&ap[colBase + t0], __float_as_uint(fmaxf(mx, 0.0f)));
            atomicMin(&an[colBase + t0], __float_as_uint(mn));
        }
    } else {
        // ---------------- QUARTER 64^2 TILE PATH ----------------------
        const int qid = bid - FULLB;
        int bi = FULLB + (qid >> 2), ti = 0;
        while (bi >= NB - ti) { bi -= NB - ti; ti++; }
        const int tj = ti + bi;
        const int q = qid & 3;
        const int rowBase = (ti << 7) + ((q >> 1) << 6);
        const int colBase = (tj << 7) + ((q & 1) << 6);

        if (tid == 0) {
            waitpan(flags + (rowBase >> 5), 2);
            waitpan(flags + (colBase >> 5), 2);
            __threadfence();
        }
        __syncthreads();

        f32x16 acc;
#pragma unroll
        for (int rr = 0; rr < 16; rr++) acc[rr] = 0.0f;

        const unsigned char* pa =
            Xf + (((size_t)(rowBase >> 5) + wr) << 16) + lane * 32;
        const unsigned char* pb =
            Xf + (((size_t)(colBase >> 5) + wc) << 16) + lane * 32;

#pragma unroll 4
        for (int t = 0; t < nt; t++) {
            const size_t off = (size_t)t << 11;
            i32x8 a = ld32(pa + off);
            i32x8 b = ld32(pb + off);
            acc = mx_mfma(a, b, acc);
        }

        const int gc = colBase + wc * 32 + m;
        const int yc = Y[gc];
        const float nc = nrm[gc];
        float cdp = -1.0f, cdn = BIGF;
#pragma unroll
        for (int reg = 0; reg < 16; reg++) {
            const int row32 = (reg & 3) + 8 * (reg >> 2) + 4 * h;
            const int gr = rowBase + wr * 32 + row32;
            const int yr = Y[gr];
            const float nr = nrm[gr];
            float d2 = nr + nc - 2.0f * acc[reg];
            float d = sqrtf(fmaxf(d2, 0.0f));
            bool same = (yr == yc);
            float vp = same ? d : -1.0f;
            float vn = same ? BIGF : d;
            cdp = fmaxf(cdp, vp);
            cdn = fminf(cdn, vn);
            float dp = vp, dn = vn;
            for (int off = 1; off < 32; off <<= 1) {
                dp = fmaxf(dp, __shfl_xor(dp, off, 64));
                dn = fminf(dn, __shfl_xor(dn, off, 64));
            }
            if (m == 0) {  // lanes 0 (h=0) and 32 (h=1): disjoint rows
                atomicMax(&ap[gr], __float_as_uint(fmaxf(dp, 0.0f)));
                atomicMin(&an[gr], __float_as_uint(dn));
            }
        }
        cdp = fmaxf(cdp, __shfl_xor(cdp, 32, 64));
        cdn = fminf(cdn, __shfl_xor(cdn, 32, 64));
        if (h == 0) {
            atomicMax(&ap[gc], __float_as_uint(fmaxf(cdp, 0.0f)));
            atomicMin(&an[gc], __float_as_uint(cdn));
        }
    }

    // Last block computes the loss (release fence before counter increment;
    // acquire fence + agent-scope atomic loads in the last block).
    __syncthreads();
    if (tid == 0) {
        __threadfence();
        s_done = atomicAdd(cnt, 1u);
    }
    __syncthreads();
    if (s_done == gridDim.x - 1) {
        __threadfence();
        float s = 0.0f;
        for (int i = tid; i < N; i += 256) {
            unsigned ua = __hip_atomic_load(&ap[i], __ATOMIC_RELAXED,
                                            __HIP_MEMORY_SCOPE_AGENT);
            unsigned ub = __hip_atomic_load(&an[i], __ATOMIC_RELAXED,
                                            __HIP_MEMORY_SCOPE_AGENT);
            s += fmaxf(__uint_as_float(ua) - __uint_as_float(ub) + MARGIN, 0.0f);
        }
        for (int off = 32; off > 0; off >>= 1) s += __shfl_xor(s, off, 64);
        if (lane == 0) lsum[wave] = s;
        __syncthreads();
        if (tid == 0)
            out[0] = (lsum[0] + lsum[1] + lsum[2] + lsum[3]) / (float)N;
    }
}

extern "C" void kernel_launch(void* const* d_in, const int* in_sizes, int n_in,
                              void* d_out, int out_size, void* d_ws, size_t ws_size,
                              hipStream_t stream) {
    const float* X = (const float*)d_in[0];
    const int* Y = (const int*)d_in[1];
    float* out = (float*)d_out;
    const int N = in_sizes[1];          // 4096
    const int K = in_sizes[0] / N;      // 2048

    char* ws = (char*)d_ws;
    unsigned char* Xf = (unsigned char*)ws;                  // N*K bytes
    float* nrm = (float*)(ws + (size_t)N * K);               // N floats
    unsigned* ap = (unsigned*)(nrm + N);                     // N
    unsigned* an = ap + N;                                   // N
    unsigned* flags = an + N;                                // N/32 = 128
    unsigned* cnt = flags + (N >> 5);                        // 1

    // Zero flags + cnt (129 words). Async memset is a graph-legal node.
    hipMemsetAsync(flags, 0, ((N >> 5) + 1) * sizeof(unsigned), stream);

    const int NB = N / 128;                       // 32
    const int ntri = NB * (NB + 1) / 2;           // 528
    const int grid = (ntri - 16) + 64;            // 512 full + 64 quarter
    fused_kernel<<<grid, 256, 0, stream>>>(X, Xf, nrm, Y, ap, an, flags,
                                           cnt, out, N, K);
}

// Round 15
// 130.371 us; speedup vs baseline: 1.1796x; 1.1796x over previous
//
#include <hip/hip_runtime.h>
#include <hip/hip_bf16.h>
#include <hip/hip_fp8.h>

typedef __attribute__((ext_vector_type(4))) int i32x4;
typedef __attribute__((ext_vector_type(8))) int i32x8;
typedef __attribute__((ext_vector_type(16))) float f32x16;

#define MARGIN 0.3f
#define BIGF 3.0e38f

__device__ __forceinline__ f32x16 mx_mfma(i32x8 a, i32x8 b, f32x16 c) {
    return __builtin_amdgcn_mfma_scale_f32_32x32x64_f8f6f4(
        a, b, c, 0 /*A fmt fp8*/, 0 /*B fmt fp8*/,
        0, 127 /*scale A = 2^0*/, 0, 127 /*scale B = 2^0*/);
}

// DENSE 32B fragment load: cell layout [half16][lane][16B]. p is already
// cell_base + lane*16. lo = bytes 0-15 (dense 1KB span across lanes),
// hi = bytes 16-31 at +1024 (dense again). Element order in the i32x8 is
// identical to the old strided layout -> MFMA operands bit-identical.
__device__ __forceinline__ i32x8 ld32d(const unsigned char* p) {
    i32x4 lo = *(const i32x4*)p;
    i32x4 hi = *(const i32x4*)(p + 1024);
    return __builtin_shufflevector(lo, hi, 0, 1, 2, 3, 4, 5, 6, 7);
}

// Wave-per-row convert: fp32 -> fp8 e4m3 (OCP) cast, fp32 row norm of the
// fp8-ROUNDED values, init ap/an/cnt. Output in DENSE fragment-native
// layout: cell (p,t) = 2 KB at p*65536 + t*2048, INTERNALLY
// [half16][lslot][16B] where lslot = (row&31) + 32*((k&63)>>5), half16 =
// ((k&31)>>4). Lane l of the gemm reads its bytes 0-15 at l*16 and 16-31
// at 1024 + l*16 -> every load instruction is a dense 1KB span (R14
// theory: the old [lane][32B] layout made every load instruction span
// 2KB at stride 32 = 16 lines x 4 lanes, saturating the per-CU address
// coalescer; that, not bytes or latency, pinned the ~60 us floor).
// Same bytes, same element order -> numerics bit-identical to R12.
__global__ __launch_bounds__(256) void convert_norm_kernel(
    const float* __restrict__ X, unsigned char* __restrict__ Xf,
    float* __restrict__ nrm, unsigned* __restrict__ ap,
    unsigned* __restrict__ an, unsigned* __restrict__ cnt, int K) {
    const int wave = threadIdx.x >> 6, lane = threadIdx.x & 63;
    const int row = blockIdx.x * 4 + wave;
    const float* xr = X + (size_t)row * K;
    const size_t pbase = ((size_t)(row >> 5)) << 16;  // p * 65536
    const int rsub = row & 31;
    float s = 0.0f;
    for (int c = lane * 8; c < K; c += 64 * 8) {
        float4 v0 = *(const float4*)(xr + c);
        float4 v1 = *(const float4*)(xr + c + 4);
        float f[8] = {v0.x, v0.y, v0.z, v0.w, v1.x, v1.y, v1.z, v1.w};
        union { unsigned char b[8]; uint2 u; } p;
#pragma unroll
        for (int i = 0; i < 8; i++) {
            __hip_fp8_e4m3 q(f[i]);       // OCP e4m3, RNE+saturate
            p.b[i] = q.__x;
            float d = (float)q;           // decoded value
            s += d * d;
        }
        // Dense-cell address: cell (row>>5, c>>6); lslot = rsub +
        // 32*((c>>5)&1); within-cell = ((c&31)>>4)*1024 + lslot*16 +
        // (c&15). c is a multiple of 8 -> aligned uint2.
        const int lslot = rsub + (((c >> 5) & 1) << 5);
        unsigned char* dst = Xf + pbase + ((size_t)(c >> 6) << 11)
                             + (((c & 31) >> 4) << 10) + (lslot << 4)
                             + (c & 15);
        *(uint2*)dst = p.u;
    }
    for (int off = 32; off > 0; off >>= 1) s += __shfl_xor(s, off, 64);
    if (lane == 0) {
        nrm[row] = s;
        ap[row] = 0u;           // dist_ap >= 0 always (self is a positive)
        an[row] = 0x7F800000u;  // +inf
        if (row == 0) *cnt = 0u;
    }
}

// TRIANGULAR fp8-MX GEMM-reduce v10 = R12 (v7) verbatim + DENSE cell
// layout. R14's fused variant regressed (spin-wait burned issue slots);
// reverted to the two-kernel R12 structure (best steady: 59.6 us, wall
// 132.2). Single lever this round: every operand load instruction is now
// a dense 1KB span (ld32d) instead of a 2KB stride-32 span -> halves the
// per-instruction line-work in the per-CU address-coalescing path, which
// the cross-round model identifies as the ~60 us floor (rate was ~3.9
// GB/s/wave, 10x below a latency bound, proportional to resident waves).
// Carried verbatim (R12-verified, absmax 0): triangle unrank, 512 full
// 128^2 + 64 quarter 64^2 blocks (1.09x balance), fragment cells, C/D
// map col=lane&31 row=(reg&3)+8*(reg>>2)+4*h, dual-sided epilogue,
// monotone uint atomics, counter-gated fused loss, launch_bounds(256,4)
// depth-1 unroll-4 (ILP proven irrelevant in R13).
__global__ __launch_bounds__(256, 4) void gemm_reduce_kernel(
    const unsigned char* __restrict__ Xf, const float* __restrict__ nrm,
    const int* __restrict__ Y, unsigned* __restrict__ ap,
    unsigned* __restrict__ an, unsigned* __restrict__ cnt,
    float* __restrict__ out, int N, int K) {
    __shared__ int sYr[128], sYc[128];
    __shared__ float sNr[128], sNc[128];
    __shared__ float redmax[4][64], redmin[4][64];  // row-side, per wave
    __shared__ float cmax[4][64], cmin[4][64];      // col-side, per wave
    __shared__ float lsum[4];
    __shared__ unsigned s_done;

    const int tid = threadIdx.x;
    const int wave = tid >> 6;
    const int lane = tid & 63;
    const int m = lane & 31;   // col within 32x32 subtile (outputs)
    const int h = lane >> 5;   // row-group (outputs)
    const int wr = wave >> 1;  // wave row (0..1)
    const int wc = wave & 1;   // wave col (0..1)

    const int NB = N >> 7;               // 32
    const int ntri = NB * (NB + 1) / 2;  // 528
    const int FULLB = ntri - 16;         // 512 full-tile blocks
    const int nt = K >> 6;               // 32 k64-steps

    if ((int)blockIdx.x < FULLB) {
        // ---------------- FULL 128^2 TILE PATH ------------------------
        int bi = blockIdx.x, ti = 0;
        while (bi >= NB - ti) { bi -= NB - ti; ti++; }
        const int tj = ti + bi;
        const int rowBase = ti << 7;
        const int colBase = tj << 7;

        if (tid < 128) {
            sYr[tid] = Y[rowBase + tid];
            sNr[tid] = nrm[rowBase + tid];
        } else {
            const int t0 = tid - 128;
            sYc[t0] = Y[colBase + t0];
            sNc[t0] = nrm[colBase + t0];
        }

        f32x16 acc[2][2];
#pragma unroll
        for (int si = 0; si < 2; si++)
#pragma unroll
            for (int sj = 0; sj < 2; sj++)
#pragma unroll
                for (int rr = 0; rr < 16; rr++) acc[si][sj][rr] = 0.0f;

        // Dense-cell base pointers: cell (p,t) at p*65536 + t*2048; this
        // lane's lo-16 at + lane*16 (hi-16 at +1024 inside ld32d).
        const unsigned char* pa[2];
        const unsigned char* pb[2];
#pragma unroll
        for (int si = 0; si < 2; si++)
            pa[si] = Xf + (((size_t)(rowBase >> 5) + wr * 2 + si) << 16) + lane * 16;
#pragma unroll
        for (int sj = 0; sj < 2; sj++)
            pb[sj] = Xf + (((size_t)(colBase >> 5) + wc * 2 + sj) << 16) + lane * 16;

#pragma unroll 4
        for (int t = 0; t < nt; t++) {
            const size_t off = (size_t)t << 11;
            i32x8 a0 = ld32d(pa[0] + off);
            i32x8 a1 = ld32d(pa[1] + off);
            i32x8 b0 = ld32d(pb[0] + off);
            i32x8 b1 = ld32d(pb[1] + off);
            acc[0][0] = mx_mfma(a0, b0, acc[0][0]);
            acc[0][1] = mx_mfma(a0, b1, acc[0][1]);
            acc[1][0] = mx_mfma(a1, b0, acc[1][0]);
            acc[1][1] = mx_mfma(a1, b1, acc[1][1]);
        }

        __syncthreads();  // sY/sN visible

        float cdp[2] = {-1.0f, -1.0f};
        float cdn[2] = {BIGF, BIGF};
#pragma unroll
        for (int si = 0; si < 2; si++)
#pragma unroll
            for (int reg = 0; reg < 16; reg++) {
                const int row64 = si * 32 + (reg & 3) + 8 * (reg >> 2) + 4 * h;
                const int rIdx = wr * 64 + row64;
                const int yr = sYr[rIdx];
                const float nr = sNr[rIdx];
                float dp = -1.0f, dn = BIGF;
#pragma unroll
                for (int sj = 0; sj < 2; sj++) {
                    const int cIdx = wc * 64 + sj * 32 + m;
                    float d2 = nr + sNc[cIdx] - 2.0f * acc[si][sj][reg];
                    float d = sqrtf(fmaxf(d2, 0.0f));
                    bool same = (yr == sYc[cIdx]);
                    float vp = same ? d : -1.0f;
                    float vn = same ? BIGF : d;
                    dp = fmaxf(dp, vp);
                    dn = fminf(dn, vn);
                    cdp[sj] = fmaxf(cdp[sj], vp);
                    cdn[sj] = fminf(cdn[sj], vn);
                }
                for (int off = 1; off < 32; off <<= 1) {
                    dp = fmaxf(dp, __shfl_xor(dp, off, 64));
                    dn = fminf(dn, __shfl_xor(dn, off, 64));
                }
                if (m == 0) {
                    redmax[wave][row64] = dp;
                    redmin[wave][row64] = dn;
                }
            }
#pragma unroll
        for (int sj = 0; sj < 2; sj++) {
            cdp[sj] = fmaxf(cdp[sj], __shfl_xor(cdp[sj], 32, 64));
            cdn[sj] = fminf(cdn[sj], __shfl_xor(cdn[sj], 32, 64));
            if (h == 0) {
                cmax[wave][sj * 32 + m] = cdp[sj];
                cmin[wave][sj * 32 + m] = cdn[sj];
            }
        }
        __syncthreads();

        if (tid < 128) {
            const int wr2 = tid >> 6, r64 = tid & 63;
            float mx = fmaxf(redmax[wr2 * 2][r64], redmax[wr2 * 2 + 1][r64]);
            float mn = fminf(redmin[wr2 * 2][r64], redmin[wr2 * 2 + 1][r64]);
            atomicMax(&ap[rowBase + tid], __float_as_uint(fmaxf(mx, 0.0f)));
            atomicMin(&an[rowBase + tid], __float_as_uint(mn));
        } else {
            const int t0 = tid - 128;
            const int wc2 = t0 >> 6, c64 = t0 & 63;
            float mx = fmaxf(cmax[wc2][c64], cmax[2 + wc2][c64]);
            float mn = fminf(cmin[wc2][c64], cmin[2 + wc2][c64]);
            atomicMax(&ap[colBase + t0], __float_as_uint(fmaxf(mx, 0.0f)));
            atomicMin(&an[colBase + t0], __float_as_uint(mn));
        }
    } else {
        // ---------------- QUARTER 64^2 TILE PATH ----------------------
        const int qid = blockIdx.x - FULLB;
        int bi = FULLB + (qid >> 2), ti = 0;
        while (bi >= NB - ti) { bi -= NB - ti; ti++; }
        const int tj = ti + bi;
        const int q = qid & 3;
        const int rowBase = (ti << 7) + ((q >> 1) << 6);
        const int colBase = (tj << 7) + ((q & 1) << 6);

        f32x16 acc;
#pragma unroll
        for (int rr = 0; rr < 16; rr++) acc[rr] = 0.0f;

        const unsigned char* pa =
            Xf + (((size_t)(rowBase >> 5) + wr) << 16) + lane * 16;
        const unsigned char* pb =
            Xf + (((size_t)(colBase >> 5) + wc) << 16) + lane * 16;

#pragma unroll 4
        for (int t = 0; t < nt; t++) {
            const size_t off = (size_t)t << 11;
            i32x8 a = ld32d(pa + off);
            i32x8 b = ld32d(pb + off);
            acc = mx_mfma(a, b, acc);
        }

        // In-wave dual-sided epilogue (32^2 subtile). Col data per-lane.
        const int gc = colBase + wc * 32 + m;
        const int yc = Y[gc];
        const float nc = nrm[gc];
        float cdp = -1.0f, cdn = BIGF;
#pragma unroll
        for (int reg = 0; reg < 16; reg++) {
            const int row32 = (reg & 3) + 8 * (reg >> 2) + 4 * h;
            const int gr = rowBase + wr * 32 + row32;
            const int yr = Y[gr];
            const float nr = nrm[gr];
            float d2 = nr + nc - 2.0f * acc[reg];
            float d = sqrtf(fmaxf(d2, 0.0f));
            bool same = (yr == yc);
            float vp = same ? d : -1.0f;
            float vn = same ? BIGF : d;
            cdp = fmaxf(cdp, vp);
            cdn = fminf(cdn, vn);
            float dp = vp, dn = vn;
            for (int off = 1; off < 32; off <<= 1) {
                dp = fmaxf(dp, __shfl_xor(dp, off, 64));
                dn = fminf(dn, __shfl_xor(dn, off, 64));
            }
            if (m == 0) {  // lanes 0 (h=0) and 32 (h=1): disjoint rows
                atomicMax(&ap[gr], __float_as_uint(fmaxf(dp, 0.0f)));
                atomicMin(&an[gr], __float_as_uint(dn));
            }
        }
        // Col-side: merge the two h-halves (disjoint row sets, same col).
        cdp = fmaxf(cdp, __shfl_xor(cdp, 32, 64));
        cdn = fminf(cdn, __shfl_xor(cdn, 32, 64));
        if (h == 0) {
            atomicMax(&ap[gc], __float_as_uint(fmaxf(cdp, 0.0f)));
            atomicMin(&an[gc], __float_as_uint(cdn));
        }
    }

    // Last block computes the loss (release fence before counter increment;
    // acquire fence + agent-scope atomic loads in the last block).
    __syncthreads();
    if (tid == 0) {
        __threadfence();
        s_done = atomicAdd(cnt, 1u);
    }
    __syncthreads();
    if (s_done == gridDim.x - 1) {
        __threadfence();
        float s = 0.0f;
        for (int i = tid; i < N; i += 256) {
            unsigned ua = __hip_atomic_load(&ap[i], __ATOMIC_RELAXED,
                                            __HIP_MEMORY_SCOPE_AGENT);
            unsigned ub = __hip_atomic_load(&an[i], __ATOMIC_RELAXED,
                                            __HIP_MEMORY_SCOPE_AGENT);
            s += fmaxf(__uint_as_float(ua) - __uint_as_float(ub) + MARGIN, 0.0f);
        }
        for (int off = 32; off > 0; off >>= 1) s += __shfl_xor(s, off, 64);
        if (lane == 0) lsum[wave] = s;
        __syncthreads();
        if (tid == 0)
            out[0] = (lsum[0] + lsum[1] + lsum[2] + lsum[3]) / (float)N;
    }
}

extern "C" void kernel_launch(void* const* d_in, const int* in_sizes, int n_in,
                              void* d_out, int out_size, void* d_ws, size_t ws_size,
                              hipStream_t stream) {
    const float* X = (const float*)d_in[0];
    const int* Y = (const int*)d_in[1];
    float* out = (float*)d_out;
    const int N = in_sizes[1];          // 4096
    const int K = in_sizes[0] / N;      // 2048

    char* ws = (char*)d_ws;
    unsigned char* Xf = (unsigned char*)ws;                         // N*K bytes
    float* nrm = (float*)(ws + (size_t)N * K);
    unsigned* ap = (unsigned*)((char*)nrm + (size_t)N * 4);
    unsigned* an = (unsigned*)((char*)ap + (size_t)N * 4);
    unsigned* cnt = (unsigned*)((char*)an + (size_t)N * 4);

    convert_norm_kernel<<<N / 4, 256, 0, stream>>>(X, Xf, nrm, ap, an, cnt, K);
    const int NB = N / 128;                       // 32
    const int ntri = NB * (NB + 1) / 2;           // 528
    const int grid = (ntri - 16) + 64;            // 512 full + 64 quarter
    gemm_reduce_kernel<<<grid, 256, 0, stream>>>(Xf, nrm, Y, ap, an, cnt,
                                                 out, N, K);
}